// Round 1
// baseline (239.371 us; speedup 1.0000x reference)
//
#include <hip/hip_runtime.h>
#include <hip/hip_bf16.h>
#include <math.h>

#define NUM_CLASSES 8192
#define FEAT_DIM    256
#define BATCH       1024
// TEMPERATURE = 0.1 -> logits = dot * 10

typedef __attribute__((ext_vector_type(8))) short bf16x8;
typedef __attribute__((ext_vector_type(4))) float f32x4;

#define GLD16(gp, lp) __builtin_amdgcn_global_load_lds(                       \
    (const __attribute__((address_space(1))) void*)(gp),                      \
    (__attribute__((address_space(3))) void*)(lp), 16, 0, 0)

__device__ __forceinline__ unsigned short f2bf(float x) {
  unsigned u = __float_as_uint(x);
  return (unsigned short)((u + 0x7fffu + ((u >> 16) & 1u)) >> 16);
}

// ---------------------------------------------------------------------------
// Phase 1: per-class sequential EMA update + bf16 convert (fused copy).
// One wave per class. Order within a class follows batch order; classes are
// independent (each reference scan step touches exactly one row).
// Also zeroes the rowsum accumulator.
// ---------------------------------------------------------------------------
__global__ __launch_bounds__(256) void ema_convert_kernel(
    const float* __restrict__ feats, const float* __restrict__ proto,
    const int* __restrict__ labels, unsigned short* __restrict__ Pb,
    float* __restrict__ rowsum) {
  if (blockIdx.x < (NUM_CLASSES / 256)) {
    rowsum[blockIdx.x * 256 + threadIdx.x] = 0.0f;
  }
  const int c    = (blockIdx.x << 2) + (threadIdx.x >> 6);  // class id, 0..8191
  const int lane = threadIdx.x & 63;

  float4 p = ((const float4*)(proto + (size_t)c * FEAT_DIM))[lane];

  for (int t = 0; t < BATCH; ++t) {
    if (labels[t] == c) {            // wave-uniform branch
      float4 f = ((const float4*)(feats + (size_t)t * FEAT_DIM))[lane];
      float4 r;
      r.x = 0.5f * p.x + 0.5f * f.x;
      r.y = 0.5f * p.y + 0.5f * f.y;
      r.z = 0.5f * p.z + 0.5f * f.z;
      r.w = 0.5f * p.w + 0.5f * f.w;
      float ss = r.x * r.x + r.y * r.y + r.z * r.z + r.w * r.w;
#pragma unroll
      for (int off = 32; off; off >>= 1) ss += __shfl_xor(ss, off);
      float inv = 1.0f / fmaxf(sqrtf(ss), 1e-12f);
      p.x = r.x * inv; p.y = r.y * inv; p.z = r.z * inv; p.w = r.w * inv;
    }
  }

  ushort4 u;
  u.x = f2bf(p.x); u.y = f2bf(p.y); u.z = f2bf(p.z); u.w = f2bf(p.w);
  ((ushort4*)(Pb + (size_t)c * FEAT_DIM))[lane] = u;
}

// ---------------------------------------------------------------------------
// Phase 2: fused GEMM (P * P^T / T) -> exp -> mask diagonal -> row sums.
// BM=BN=128, BK=64, 4 waves (2x2), mfma_f32_16x16x32_bf16.
// LDS staged via global_load_lds(16B) with pre-swizzled global source;
// ds_read_b128 with chunk ^= (row&7) swizzle (bank-conflict fix).
// ---------------------------------------------------------------------------
#define BM 128
#define BK 64

__global__ __launch_bounds__(256) void gemm_rowsum_kernel(
    const unsigned short* __restrict__ P, float* __restrict__ rowsum) {
  __shared__ __align__(16) char As[BM * BK * 2];  // 16 KB
  __shared__ __align__(16) char Bs[BM * BK * 2];  // 16 KB

  const int bid  = blockIdx.x;
  const int brow = bid >> 6;          // 64 row-blocks
  const int bcol = bid & 63;          // 64 col-blocks
  const int tid  = threadIdx.x;
  const int wid  = tid >> 6;
  const int lane = tid & 63;
  const int wm   = wid >> 1;          // 0..1
  const int wn   = wid & 1;           // 0..1

  f32x4 acc[4][4] = {};

  // staging geometry: 16 wave-loads of 1KB per tile; wave does 4 for A, 4 for B
  const int r_loc  = (lane >> 3);         // 0..7 row within wave-load
  const int c_phys = (lane & 7);          // physical 16B chunk
  const int c_src  = c_phys ^ r_loc;      // logical chunk = phys ^ (row&7)

  for (int kt = 0; kt < FEAT_DIM / BK; ++kt) {
#pragma unroll
    for (int q = 0; q < 4; ++q) {
      const int Lld = wid * 4 + q;        // 0..15
      const int r   = Lld * 8 + r_loc;    // tile row 0..127  (r&7 == r_loc)
      const size_t goffA = (size_t)(brow * BM + r) * FEAT_DIM + kt * BK + c_src * 8;
      const size_t goffB = (size_t)(bcol * BM + r) * FEAT_DIM + kt * BK + c_src * 8;
      GLD16(P + goffA, As + Lld * 1024);
      GLD16(P + goffB, Bs + Lld * 1024);
    }
    __syncthreads();

    const int g  = lane >> 4;   // 0..3
    const int rl = lane & 15;   // 0..15
#pragma unroll
    for (int kk = 0; kk < 2; ++kk) {
      bf16x8 a[4], b[4];
#pragma unroll
      for (int mi = 0; mi < 4; ++mi) {
        const int row   = wm * 64 + mi * 16 + rl;
        const int chunk = (kk * 4 + g) ^ (row & 7);
        a[mi] = *(const bf16x8*)(As + row * (BK * 2) + chunk * 16);
      }
#pragma unroll
      for (int ni = 0; ni < 4; ++ni) {
        const int row   = wn * 64 + ni * 16 + rl;
        const int chunk = (kk * 4 + g) ^ (row & 7);
        b[ni] = *(const bf16x8*)(Bs + row * (BK * 2) + chunk * 16);
      }
#pragma unroll
      for (int mi = 0; mi < 4; ++mi)
#pragma unroll
        for (int ni = 0; ni < 4; ++ni)
          acc[mi][ni] = __builtin_amdgcn_mfma_f32_16x16x32_bf16(
              a[mi], b[ni], acc[mi][ni], 0, 0, 0);
    }
    __syncthreads();
  }

  // Epilogue: logits = acc*10 -> exp -> zero diagonal -> per-row sums.
  // C/D layout: col = lane&15, row = (lane>>4)*4 + reg  [m89/m91]
  const int rl = lane & 15;
  const int g  = lane >> 4;
#pragma unroll
  for (int mi = 0; mi < 4; ++mi) {
    const int growb = brow * BM + wm * 64 + mi * 16 + g * 4;
#pragma unroll
    for (int v = 0; v < 4; ++v) {
      const int grow = growb + v;
      float s = 0.0f;
#pragma unroll
      for (int ni = 0; ni < 4; ++ni) {
        const int gcol = bcol * BM + wn * 64 + ni * 16 + rl;
        float e = __expf(10.0f * acc[mi][ni][v]);
        if (grow == gcol) e = 0.0f;   // mask diagonal
        s += e;
      }
      s += __shfl_xor(s, 1);
      s += __shfl_xor(s, 2);
      s += __shfl_xor(s, 4);
      s += __shfl_xor(s, 8);
      if (rl == 0) atomicAdd(&rowsum[grow], s);
    }
  }
}

// ---------------------------------------------------------------------------
// Phase 3: loss = mean(log(rowsum / 8191))
// ---------------------------------------------------------------------------
__global__ __launch_bounds__(256) void finalize_kernel(
    const float* __restrict__ rowsum, float* __restrict__ out) {
  const int tid = threadIdx.x;
  float s = 0.0f;
  for (int i = tid; i < NUM_CLASSES; i += 256) {
    s += logf(rowsum[i] * (1.0f / (float)(NUM_CLASSES - 1)));
  }
#pragma unroll
  for (int off = 32; off; off >>= 1) s += __shfl_xor(s, off);
  __shared__ float red[4];
  if ((tid & 63) == 0) red[tid >> 6] = s;
  __syncthreads();
  if (tid == 0)
    out[0] = (red[0] + red[1] + red[2] + red[3]) * (1.0f / (float)NUM_CLASSES);
}

// ---------------------------------------------------------------------------
extern "C" void kernel_launch(void* const* d_in, const int* in_sizes, int n_in,
                              void* d_out, int out_size, void* d_ws, size_t ws_size,
                              hipStream_t stream) {
  const float* feats  = (const float*)d_in[0];
  const float* proto  = (const float*)d_in[1];
  const int*   labels = (const int*)d_in[2];
  float*       out    = (float*)d_out;

  unsigned short* Pb     = (unsigned short*)d_ws;                        // 4 MB bf16 P
  float*          rowsum = (float*)((char*)d_ws + (size_t)NUM_CLASSES * FEAT_DIM * 2);

  ema_convert_kernel<<<NUM_CLASSES / 4, 256, 0, stream>>>(feats, proto, labels, Pb, rowsum);
  gemm_rowsum_kernel<<<64 * 64, 256, 0, stream>>>(Pb, rowsum);
  finalize_kernel<<<1, 256, 0, stream>>>(rowsum, out);
}

// Round 2
// 89.986 us; speedup vs baseline: 2.6601x; 2.6601x over previous
//
#include <hip/hip_runtime.h>
#include <hip/hip_bf16.h>
#include <math.h>

#define NUM_CLASSES 8192
#define FEAT_DIM    256
#define BATCH       1024
// TEMPERATURE = 0.1 -> logits = dot * 10

typedef __attribute__((ext_vector_type(8))) short bf16x8;
typedef __attribute__((ext_vector_type(4))) float f32x4;

#define GLD16(gp, lp) __builtin_amdgcn_global_load_lds(                       \
    (const __attribute__((address_space(1))) void*)(gp),                      \
    (__attribute__((address_space(3))) void*)(lp), 16, 0, 0)

__device__ __forceinline__ unsigned short f2bf(float x) {
  unsigned u = __float_as_uint(x);
  return (unsigned short)((u + 0x7fffu + ((u >> 16) & 1u)) >> 16);
}

// ---------------------------------------------------------------------------
// Phase 0: build CSR (per-class, batch-ordered update list).
// One block, 1024 threads. Histogram + rank + prefix-scan, all in LDS.
// ---------------------------------------------------------------------------
__global__ __launch_bounds__(1024) void prep_kernel(
    const int* __restrict__ labels, int* __restrict__ offs,
    int* __restrict__ order) {
  __shared__ int lab_s[BATCH];
  __shared__ int cnt_s[NUM_CLASSES];   // counts, later offsets (32 KB)
  __shared__ int wtot[16];
  const int tid = threadIdx.x;

  for (int i = tid; i < NUM_CLASSES; i += 1024) cnt_s[i] = 0;
  lab_s[tid] = labels[tid];
  __syncthreads();

  const int lab = lab_s[tid];
  int rank = 0;                         // order among same-label earlier entries
  for (int t = 0; t < tid; ++t) rank += (lab_s[t] == lab);
  atomicAdd(&cnt_s[lab], 1);
  __syncthreads();

  // prefix sum over 8192 counts: each thread owns 8
  const int base = tid * 8;
  int local[8];
  int s = 0;
#pragma unroll
  for (int k = 0; k < 8; ++k) { local[k] = s; s += cnt_s[base + k]; }
  __syncthreads();                      // all reads of cnt_s done before overwrite

  // inclusive scan of per-thread totals: wave scan + cross-wave scan
  int x = s;
#pragma unroll
  for (int d = 1; d < 64; d <<= 1) {
    int y = __shfl_up(x, d);
    if ((tid & 63) >= d) x += y;
  }
  if ((tid & 63) == 63) wtot[tid >> 6] = x;
  __syncthreads();
  if (tid < 16) {
    int w = wtot[tid];
#pragma unroll
    for (int d = 1; d < 16; d <<= 1) {
      int y = __shfl_up(w, d);
      if (tid >= d) w += y;
    }
    wtot[tid] = w;
  }
  __syncthreads();
  const int wbase = (tid >= 64) ? wtot[(tid >> 6) - 1] : 0;
  const int excl  = wbase + x - s;      // exclusive prefix of this thread's chunk

#pragma unroll
  for (int k = 0; k < 8; ++k) {
    const int o = excl + local[k];
    cnt_s[base + k] = o;                // LDS copy for scatter below
    offs[base + k]  = o;                // global for the EMA kernel
  }
  if (tid == 1023) offs[NUM_CLASSES] = BATCH;
  __syncthreads();

  order[cnt_s[lab] + rank] = tid;
}

// ---------------------------------------------------------------------------
// Phase 1: per-class EMA update (CSR-driven) + bf16 convert + rowsum zero.
// One wave per class; most classes have 0 updates -> pure copy/convert.
// ---------------------------------------------------------------------------
__global__ __launch_bounds__(256) void ema_convert_kernel(
    const float* __restrict__ feats, const float* __restrict__ proto,
    const int* __restrict__ offs, const int* __restrict__ order,
    unsigned short* __restrict__ Pb, float* __restrict__ rowsum) {
  if (blockIdx.x < (NUM_CLASSES / 256)) {
    rowsum[blockIdx.x * 256 + threadIdx.x] = 0.0f;
  }
  const int c    = (blockIdx.x << 2) + (threadIdx.x >> 6);  // class id
  const int lane = threadIdx.x & 63;

  float4 p = ((const float4*)(proto + (size_t)c * FEAT_DIM))[lane];

  const int qs = offs[c], qe = offs[c + 1];
  for (int q = qs; q < qe; ++q) {
    const int t = order[q];
    float4 f = ((const float4*)(feats + (size_t)t * FEAT_DIM))[lane];
    float4 r;
    r.x = 0.5f * p.x + 0.5f * f.x;
    r.y = 0.5f * p.y + 0.5f * f.y;
    r.z = 0.5f * p.z + 0.5f * f.z;
    r.w = 0.5f * p.w + 0.5f * f.w;
    float ss = r.x * r.x + r.y * r.y + r.z * r.z + r.w * r.w;
#pragma unroll
    for (int off = 32; off; off >>= 1) ss += __shfl_xor(ss, off);
    float inv = 1.0f / fmaxf(sqrtf(ss), 1e-12f);
    p.x = r.x * inv; p.y = r.y * inv; p.z = r.z * inv; p.w = r.w * inv;
  }

  ushort4 u;
  u.x = f2bf(p.x); u.y = f2bf(p.y); u.z = f2bf(p.z); u.w = f2bf(p.w);
  ((ushort4*)(Pb + (size_t)c * FEAT_DIM))[lane] = u;
}

// ---------------------------------------------------------------------------
// Phase 2: fused GEMM (P * P^T / T) -> exp -> mask -> row sums.
// Symmetry-halved: only upper-triangular 128x128 blocks (bi<=bj).
// Off-diagonal blocks add row-sums to rows[bi-range] AND col-sums to
// rows[bj-range] (S symmetric). Diagonal blocks mask the diagonal.
// BM=BN=128, BK=64, 4 waves (2x2), mfma_f32_16x16x32_bf16,
// global_load_lds(16B) with pre-swizzled source + XOR-swizzled ds_read_b128.
// ---------------------------------------------------------------------------
#define BM 128
#define BK 64
#define NB (NUM_CLASSES / BM)           // 64 block-rows
#define NTRI (NB * (NB + 1) / 2)        // 2080 triangular blocks

__global__ __launch_bounds__(256) void gemm_rowsum_kernel(
    const unsigned short* __restrict__ P, float* __restrict__ rowsum) {
  __shared__ __align__(16) char As[BM * BK * 2];  // 16 KB
  __shared__ __align__(16) char Bs[BM * BK * 2];  // 16 KB

  // triangular block mapping: bid -> (bi, bj), bi <= bj
  int rem = blockIdx.x, bi = 0;
  while (rem >= (NB - bi)) { rem -= (NB - bi); ++bi; }
  const int bj = bi + rem;

  const int tid  = threadIdx.x;
  const int wid  = tid >> 6;
  const int lane = tid & 63;
  const int wm   = wid >> 1;          // 0..1
  const int wn   = wid & 1;           // 0..1

  f32x4 acc[4][4] = {};

  const int r_loc  = (lane >> 3);         // 0..7 row within wave-load
  const int c_phys = (lane & 7);          // physical 16B chunk
  const int c_src  = c_phys ^ r_loc;      // pre-swizzled source chunk

  for (int kt = 0; kt < FEAT_DIM / BK; ++kt) {
#pragma unroll
    for (int q = 0; q < 4; ++q) {
      const int Lld = wid * 4 + q;        // 0..15
      const int r   = Lld * 8 + r_loc;    // tile row 0..127
      const size_t goffA = (size_t)(bi * BM + r) * FEAT_DIM + kt * BK + c_src * 8;
      const size_t goffB = (size_t)(bj * BM + r) * FEAT_DIM + kt * BK + c_src * 8;
      GLD16(P + goffA, As + Lld * 1024);
      GLD16(P + goffB, Bs + Lld * 1024);
    }
    __syncthreads();

    const int g  = lane >> 4;   // 0..3
    const int rl = lane & 15;   // 0..15
#pragma unroll
    for (int kk = 0; kk < 2; ++kk) {
      bf16x8 a[4], b[4];
#pragma unroll
      for (int mi = 0; mi < 4; ++mi) {
        const int row   = wm * 64 + mi * 16 + rl;
        const int chunk = (kk * 4 + g) ^ (row & 7);
        a[mi] = *(const bf16x8*)(As + row * (BK * 2) + chunk * 16);
      }
#pragma unroll
      for (int ni = 0; ni < 4; ++ni) {
        const int row   = wn * 64 + ni * 16 + rl;
        const int chunk = (kk * 4 + g) ^ (row & 7);
        b[ni] = *(const bf16x8*)(Bs + row * (BK * 2) + chunk * 16);
      }
#pragma unroll
      for (int mi = 0; mi < 4; ++mi)
#pragma unroll
        for (int ni = 0; ni < 4; ++ni)
          acc[mi][ni] = __builtin_amdgcn_mfma_f32_16x16x32_bf16(
              a[mi], b[ni], acc[mi][ni], 0, 0, 0);
    }
    __syncthreads();
  }

  // Epilogue. C/D layout: col = lane&15, row = (lane>>4)*4 + reg  [m89/m91]
  const int rl   = lane & 15;
  const int g    = lane >> 4;
  const bool diag = (bi == bj);
  float col[4] = {0.0f, 0.0f, 0.0f, 0.0f};   // per-ni column partial sums

#pragma unroll
  for (int mi = 0; mi < 4; ++mi) {
    const int growb = bi * BM + wm * 64 + mi * 16 + g * 4;
#pragma unroll
    for (int v = 0; v < 4; ++v) {
      const int grow = growb + v;
      float rs = 0.0f;
#pragma unroll
      for (int ni = 0; ni < 4; ++ni) {
        const int gcol = bj * BM + wn * 64 + ni * 16 + rl;
        float e = __expf(10.0f * acc[mi][ni][v]);
        if (diag && grow == gcol) e = 0.0f;   // mask diagonal
        rs += e;
        col[ni] += e;
      }
      rs += __shfl_xor(rs, 1);
      rs += __shfl_xor(rs, 2);
      rs += __shfl_xor(rs, 4);
      rs += __shfl_xor(rs, 8);
      if (rl == 0) atomicAdd(&rowsum[grow], rs);
    }
  }

  if (!diag) {
    // column sums -> rows of block bj (S symmetric)
#pragma unroll
    for (int ni = 0; ni < 4; ++ni) {
      float cs = col[ni];
      cs += __shfl_xor(cs, 16);
      cs += __shfl_xor(cs, 32);
      if (g == 0) {
        const int gcol = bj * BM + wn * 64 + ni * 16 + rl;
        atomicAdd(&rowsum[gcol], cs);
      }
    }
  }
}

// ---------------------------------------------------------------------------
// Phase 3: loss = mean(log(rowsum / 8191))
// ---------------------------------------------------------------------------
__global__ __launch_bounds__(256) void finalize_kernel(
    const float* __restrict__ rowsum, float* __restrict__ out) {
  const int tid = threadIdx.x;
  float s = 0.0f;
  for (int i = tid; i < NUM_CLASSES; i += 256) {
    s += logf(rowsum[i] * (1.0f / (float)(NUM_CLASSES - 1)));
  }
#pragma unroll
  for (int off = 32; off; off >>= 1) s += __shfl_xor(s, off);
  __shared__ float red[4];
  if ((tid & 63) == 0) red[tid >> 6] = s;
  __syncthreads();
  if (tid == 0)
    out[0] = (red[0] + red[1] + red[2] + red[3]) * (1.0f / (float)NUM_CLASSES);
}

// ---------------------------------------------------------------------------
extern "C" void kernel_launch(void* const* d_in, const int* in_sizes, int n_in,
                              void* d_out, int out_size, void* d_ws, size_t ws_size,
                              hipStream_t stream) {
  const float* feats  = (const float*)d_in[0];
  const float* proto  = (const float*)d_in[1];
  const int*   labels = (const int*)d_in[2];
  float*       out    = (float*)d_out;

  char* ws = (char*)d_ws;
  unsigned short* Pb     = (unsigned short*)ws;                 // 4 MB bf16 P
  size_t off = (size_t)NUM_CLASSES * FEAT_DIM * 2;
  float* rowsum = (float*)(ws + off);   off += (size_t)NUM_CLASSES * 4;
  int*   offs   = (int*)(ws + off);     off += (size_t)(NUM_CLASSES + 1) * 4;
  int*   order  = (int*)(ws + off);

  prep_kernel<<<1, 1024, 0, stream>>>(labels, offs, order);
  ema_convert_kernel<<<NUM_CLASSES / 4, 256, 0, stream>>>(feats, proto, offs,
                                                          order, Pb, rowsum);
  gemm_rowsum_kernel<<<NTRI, 256, 0, stream>>>(Pb, rowsum);
  finalize_kernel<<<1, 256, 0, stream>>>(rowsum, out);
}